// Round 1
// baseline (2066.537 us; speedup 1.0000x reference)
//
#include <hip/hip_runtime.h>
#include <math.h>

#define N_ 100000
#define E_ 3200000
#define K_ 1024
#define D_ 11

static inline size_t align512(size_t x) { return (x + 511) & ~(size_t)511; }

// ---------------- init: zero/seed all accumulated ws buffers ----------------
__global__ void k_init(int* __restrict__ deg, float* __restrict__ u,
                       float* __restrict__ probs_raw, unsigned char* __restrict__ flag,
                       float* __restrict__ xmean) {
    int i = blockIdx.x * blockDim.x + threadIdx.x;
    if (i < N_) { deg[i] = 1; probs_raw[i] = 0.f; flag[i] = 0; }  // deg=1: self-loop
    if (i < N_ * D_) u[i] = 0.f;
    if (i < 64) xmean[i] = 0.f;
}

__global__ void k_flags(const int* __restrict__ ready, unsigned char* __restrict__ flag) {
    int i = blockIdx.x * blockDim.x + threadIdx.x;
    if (i < K_) flag[ready[i]] = 1;
}

// ---------------- degree count (out-degree at src, +1 self loop in init) ----
__global__ void k_deg(const int* __restrict__ src, int* __restrict__ deg) {
    int e = blockIdx.x * blockDim.x + threadIdx.x;
    if (e < E_) atomicAdd(&deg[src[e]], 1);
}

__global__ void k_dis(const int* __restrict__ deg, float* __restrict__ dis) {
    int i = blockIdx.x * blockDim.x + threadIdx.x;
    if (i < N_) dis[i] = rsqrtf((float)deg[i]);
}

// ---------------- conv1 edge aggregation on RAW x (11 feats, dis[src] deferred)
__global__ void k_agg(const int* __restrict__ src, const int* __restrict__ dst,
                      const float* __restrict__ dis, const float* __restrict__ x,
                      float* __restrict__ u) {
    int e = blockIdx.x * blockDim.x + threadIdx.x;
    if (e >= E_) return;
    int s = src[e], d = dst[e];
    float w = dis[d];
    const float* xr = x + (size_t)d * D_;
    float* ur = u + (size_t)s * D_;
#pragma unroll
    for (int f = 0; f < D_; f++) atomicAdd(&ur[f], w * xr[f]);
}

// ---------------- per-node: g=dis*(u+dis*x); h=relu(gW1+b1); h2=[h,x]@W2; mean(h)
__global__ __launch_bounds__(256) void k_node(
    const float* __restrict__ x, const float* __restrict__ u,
    const float* __restrict__ dis,
    const float* __restrict__ W1, const float* __restrict__ b1,
    const float* __restrict__ W2,
    float* __restrict__ h2, float* __restrict__ xmean) {
    __shared__ float sW1[D_ * 64];
    __shared__ float sb1[64];
    __shared__ float sW2[75];
    __shared__ float smean[64];
    int t = threadIdx.x;
    for (int k = t; k < D_ * 64; k += 256) sW1[k] = W1[k];
    if (t < 64) { sb1[t] = b1[t]; smean[t] = 0.f; }
    if (t < 75) sW2[t] = W2[t];
    __syncthreads();

    int i = blockIdx.x * 256 + t;
    if (i < N_) {
        float di = dis[i];
        float g[D_], xr[D_];
#pragma unroll
        for (int j = 0; j < D_; j++) {
            xr[j] = x[(size_t)i * D_ + j];
            g[j]  = di * (u[(size_t)i * D_ + j] + di * xr[j]);
        }
        float h2v = 0.f;
        int f0 = t & 63;  // lane-stagger: no same-address LDS atomic collisions
#pragma unroll 8
        for (int k = 0; k < 64; k++) {
            int f = (f0 + k) & 63;
            float a = sb1[f];
#pragma unroll
            for (int j = 0; j < D_; j++) a = fmaf(g[j], sW1[j * 64 + f], a);
            float hf = fmaxf(a, 0.f);
            atomicAdd(&smean[f], hf);
            h2v = fmaf(hf, sW2[f], h2v);
        }
#pragma unroll
        for (int j = 0; j < D_; j++) h2v = fmaf(xr[j], sW2[64 + j], h2v);
        h2[i] = h2v;
    }
    __syncthreads();
    if (t < 64) atomicAdd(&xmean[t], smean[t]);
}

// ---------------- conv2 edge aggregation, gated to ready src nodes ----------
__global__ void k_probs(const int* __restrict__ src, const int* __restrict__ dst,
                        const unsigned char* __restrict__ flag,
                        const float* __restrict__ dis, const float* __restrict__ h2,
                        float* __restrict__ probs_raw) {
    int e = blockIdx.x * blockDim.x + threadIdx.x;
    if (e >= E_) return;
    int s = src[e];
    if (flag[s]) {
        int d = dst[e];
        atomicAdd(&probs_raw[s], dis[d] * h2[d]);
    }
}

// ---------------- finalize: logits, prob_nothing, v, softmax ----------------
__global__ __launch_bounds__(1024) void k_final(
    const int* __restrict__ ready, const float* __restrict__ dis,
    const float* __restrict__ h2, const float* __restrict__ probs_raw,
    const float* __restrict__ xmean,
    const float* __restrict__ b2,
    const float* __restrict__ Wd, const float* __restrict__ bd,
    const float* __restrict__ Wv, const float* __restrict__ bv,
    float* __restrict__ out) {
    __shared__ float xm[64];
    __shared__ float red[1024];
    __shared__ float s_max, s_sum, s_pn, s_v;
    int t = threadIdx.x;
    if (t < 64) xm[t] = xmean[t] * (1.0f / N_);
    __syncthreads();
    if (t == 0) {
        float pn = bd[0], vv = bv[0];
        for (int f = 0; f < 64; f++) { pn += xm[f] * Wd[f]; vv += xm[f] * Wv[f]; }
        s_pn = pn; s_v = vv;
    }
    int r = ready[t];
    float dr = dis[r];
    float l = dr * (probs_raw[r] + dr * h2[r]) + b2[0];
    __syncthreads();
    float pn = s_pn;
    red[t] = (t == 0) ? fmaxf(l, pn) : l;
    __syncthreads();
    for (int sft = 512; sft > 0; sft >>= 1) {
        if (t < sft) red[t] = fmaxf(red[t], red[t + sft]);
        __syncthreads();
    }
    if (t == 0) s_max = red[0];
    __syncthreads();
    float m = s_max;
    float el = expf(l - m);
    red[t] = el + ((t == 0) ? expf(pn - m) : 0.f);
    __syncthreads();
    for (int sft = 512; sft > 0; sft >>= 1) {
        if (t < sft) red[t] += red[t + sft];
        __syncthreads();
    }
    if (t == 0) s_sum = red[0];
    __syncthreads();
    float inv = 1.0f / s_sum;
    out[t] = el * inv;
    if (t == 0) {
        out[K_] = expf(pn - m) * inv;   // prob_nothing slot
        out[K_ + 1] = s_v;              // v
    }
}

extern "C" void kernel_launch(void* const* d_in, const int* in_sizes, int n_in,
                              void* d_out, int out_size, void* d_ws, size_t ws_size,
                              hipStream_t stream) {
    const float* x    = (const float*)d_in[0];
    const int*   ei   = (const int*)d_in[1];
    const int*   src  = ei;
    const int*   dst  = ei + E_;
    const int*   ready= (const int*)d_in[2];
    const float* W1   = (const float*)d_in[3];
    const float* b1   = (const float*)d_in[4];
    const float* W2   = (const float*)d_in[5];
    const float* b2   = (const float*)d_in[6];
    const float* Wd   = (const float*)d_in[7];
    const float* bd   = (const float*)d_in[8];
    const float* Wv   = (const float*)d_in[9];
    const float* bv   = (const float*)d_in[10];
    float* out = (float*)d_out;

    char* ws = (char*)d_ws;
    size_t o = 0;
    int*   deg       = (int*)(ws + o);            o += align512(N_ * sizeof(int));
    float* dis       = (float*)(ws + o);          o += align512(N_ * sizeof(float));
    float* u         = (float*)(ws + o);          o += align512((size_t)N_ * D_ * sizeof(float));
    float* h2        = (float*)(ws + o);          o += align512(N_ * sizeof(float));
    float* probs_raw = (float*)(ws + o);          o += align512(N_ * sizeof(float));
    unsigned char* flag = (unsigned char*)(ws + o); o += align512(N_);
    float* xmean     = (float*)(ws + o);          o += align512(64 * sizeof(float));

    const int B = 256;
    int g_init  = (N_ * D_ + B - 1) / B;
    int g_edge  = (E_ + B - 1) / B;
    int g_node  = (N_ + B - 1) / B;

    k_init <<<g_init, B, 0, stream>>>(deg, u, probs_raw, flag, xmean);
    k_flags<<<(K_ + B - 1) / B, B, 0, stream>>>(ready, flag);
    k_deg  <<<g_edge, B, 0, stream>>>(src, deg);
    k_dis  <<<g_node, B, 0, stream>>>(deg, dis);
    k_agg  <<<g_edge, B, 0, stream>>>(src, dst, dis, x, u);
    k_node <<<g_node, B, 0, stream>>>(x, u, dis, W1, b1, W2, h2, xmean);
    k_probs<<<g_edge, B, 0, stream>>>(src, dst, flag, dis, h2, probs_raw);
    k_final<<<1, 1024, 0, stream>>>(ready, dis, h2, probs_raw, xmean,
                                    b2, Wd, bd, Wv, bv, out);
}

// Round 2
// 623.509 us; speedup vs baseline: 3.3144x; 3.3144x over previous
//
#include <hip/hip_runtime.h>
#include <math.h>

#define N_ 100000
#define E_ 3200000
#define K_ 1024
#define D_ 11

static inline size_t align512(size_t x) { return (x + 511) & ~(size_t)511; }

// ---------------- init: zero counters ----------------
__global__ void k_init(int* __restrict__ cnt, float* __restrict__ xmean) {
    int i = blockIdx.x * blockDim.x + threadIdx.x;
    if (i < N_) cnt[i] = 0;
    if (i < 64) xmean[i] = 0.f;
}

// ---------------- count out-degree at src; record per-edge rank ----------------
__global__ void k_cnt(const int* __restrict__ src, int* __restrict__ cnt,
                      int* __restrict__ rank) {
    int e = blockIdx.x * blockDim.x + threadIdx.x;
    if (e < E_) rank[e] = atomicAdd(&cnt[src[e]], 1);
}

// ---------------- single-block exclusive scan of cnt -> rowstart; dis ----------------
__global__ __launch_bounds__(1024) void k_scan(const int* __restrict__ cnt,
                                               int* __restrict__ rowstart,
                                               float* __restrict__ dis) {
    __shared__ int part[1024];
    int t = threadIdx.x;
    const int CH = (N_ + 1023) / 1024;  // 98
    int lo = t * CH, hi = min(lo + CH, N_);
    int s = 0;
    for (int i = lo; i < hi; i++) s += cnt[i];
    part[t] = s;
    __syncthreads();
    for (int off = 1; off < 1024; off <<= 1) {
        int v = (t >= off) ? part[t - off] : 0;
        __syncthreads();
        part[t] += v;
        __syncthreads();
    }
    int run = (t > 0) ? part[t - 1] : 0;  // exclusive base for this chunk
    for (int i = lo; i < hi; i++) {
        rowstart[i] = run;
        int c = cnt[i];
        run += c;
        dis[i] = rsqrtf((float)(c + 1));  // +1 self-loop
    }
    if (t == 1023) rowstart[N_] = part[1023];  // = E_
}

// ---------------- scatter dst into CSR slots (no atomics) ----------------
__global__ void k_scatter(const int* __restrict__ src, const int* __restrict__ dst,
                          const int* __restrict__ rank, const int* __restrict__ rowstart,
                          int* __restrict__ nbr) {
    int e = blockIdx.x * blockDim.x + threadIdx.x;
    if (e < E_) nbr[rowstart[src[e]] + rank[e]] = dst[e];
}

// ---------------- pad x [N,11] -> x12 [N,12] for float4 gathers ----------------
__global__ void k_pad(const float* __restrict__ x, float* __restrict__ x12) {
    int i = blockIdx.x * blockDim.x + threadIdx.x;
    if (i >= N_ * 12) return;
    int n = i / 12, j = i - n * 12;
    x12[i] = (j < D_) ? x[n * D_ + j] : 0.f;
}

// ---------------- per-node: gather-agg + xW1+b1, relu, h2=[h,x]@W2, mean(h) ----
__global__ __launch_bounds__(256) void k_node(
    const float* __restrict__ x12, const int* __restrict__ nbr,
    const int* __restrict__ rowstart, const float* __restrict__ dis,
    const float* __restrict__ W1, const float* __restrict__ b1,
    const float* __restrict__ W2,
    float* __restrict__ h2, float* __restrict__ xmean) {
    __shared__ float sW1[D_ * 64];
    __shared__ float sb1[64];
    __shared__ float sW2[75];
    __shared__ float smean[64];
    int t = threadIdx.x;
    for (int k = t; k < D_ * 64; k += 256) sW1[k] = W1[k];
    if (t < 64) { sb1[t] = b1[t]; smean[t] = 0.f; }
    if (t < 75) sW2[t] = W2[t];
    __syncthreads();

    int i = blockIdx.x * 256 + t;
    if (i < N_) {
        int base = rowstart[i], end = rowstart[i + 1];
        float acc[D_];
#pragma unroll
        for (int j = 0; j < D_; j++) acc[j] = 0.f;
        for (int p = base; p < end; p++) {
            int d = nbr[p];
            float w = dis[d];
            const float4* xr = (const float4*)(x12 + (size_t)d * 12);
            float4 a0 = xr[0], a1 = xr[1], a2 = xr[2];
            acc[0] = fmaf(w, a0.x, acc[0]);
            acc[1] = fmaf(w, a0.y, acc[1]);
            acc[2] = fmaf(w, a0.z, acc[2]);
            acc[3] = fmaf(w, a0.w, acc[3]);
            acc[4] = fmaf(w, a1.x, acc[4]);
            acc[5] = fmaf(w, a1.y, acc[5]);
            acc[6] = fmaf(w, a1.z, acc[6]);
            acc[7] = fmaf(w, a1.w, acc[7]);
            acc[8] = fmaf(w, a2.x, acc[8]);
            acc[9] = fmaf(w, a2.y, acc[9]);
            acc[10] = fmaf(w, a2.z, acc[10]);
        }
        float di = dis[i];
        float g[D_], xr_[D_];
        const float4* xs = (const float4*)(x12 + (size_t)i * 12);
        float4 s0 = xs[0], s1 = xs[1], s2 = xs[2];
        xr_[0]=s0.x; xr_[1]=s0.y; xr_[2]=s0.z; xr_[3]=s0.w;
        xr_[4]=s1.x; xr_[5]=s1.y; xr_[6]=s1.z; xr_[7]=s1.w;
        xr_[8]=s2.x; xr_[9]=s2.y; xr_[10]=s2.z;
#pragma unroll
        for (int j = 0; j < D_; j++) g[j] = di * (acc[j] + di * xr_[j]);

        float h2v = 0.f;
        int f0 = t & 63;  // lane-stagger: no same-address LDS atomic collisions
#pragma unroll 8
        for (int k = 0; k < 64; k++) {
            int f = (f0 + k) & 63;
            float a = sb1[f];
#pragma unroll
            for (int j = 0; j < D_; j++) a = fmaf(g[j], sW1[j * 64 + f], a);
            float hf = fmaxf(a, 0.f);
            atomicAdd(&smean[f], hf);
            h2v = fmaf(hf, sW2[f], h2v);
        }
#pragma unroll
        for (int j = 0; j < D_; j++) h2v = fmaf(xr_[j], sW2[64 + j], h2v);
        h2[i] = h2v;
    }
    __syncthreads();
    if (t < 64) atomicAdd(&xmean[t], smean[t]);
}

// ---------------- conv2 gather at ready nodes only (1 wave per node) --------
__global__ __launch_bounds__(64) void k_ready(
    const int* __restrict__ ready, const int* __restrict__ rowstart,
    const int* __restrict__ nbr, const float* __restrict__ dis,
    const float* __restrict__ h2, float* __restrict__ pr) {
    int b = blockIdx.x;
    int r = ready[b];
    int base = rowstart[r], end = rowstart[r + 1];
    float s = 0.f;
    for (int p = base + threadIdx.x; p < end; p += 64) {
        int d = nbr[p];
        s += dis[d] * h2[d];
    }
#pragma unroll
    for (int off = 32; off > 0; off >>= 1) s += __shfl_down(s, off);
    if (threadIdx.x == 0) pr[b] = s;
}

// ---------------- finalize: logits, prob_nothing, v, softmax ----------------
__global__ __launch_bounds__(1024) void k_final(
    const int* __restrict__ ready, const float* __restrict__ dis,
    const float* __restrict__ h2, const float* __restrict__ pr,
    const float* __restrict__ xmean,
    const float* __restrict__ b2,
    const float* __restrict__ Wd, const float* __restrict__ bd,
    const float* __restrict__ Wv, const float* __restrict__ bv,
    float* __restrict__ out) {
    __shared__ float xm[64];
    __shared__ float red[1024];
    __shared__ float s_max, s_sum, s_pn, s_v;
    int t = threadIdx.x;
    if (t < 64) xm[t] = xmean[t] * (1.0f / N_);
    __syncthreads();
    if (t == 0) {
        float pn = bd[0], vv = bv[0];
        for (int f = 0; f < 64; f++) { pn += xm[f] * Wd[f]; vv += xm[f] * Wv[f]; }
        s_pn = pn; s_v = vv;
    }
    int r = ready[t];
    float dr = dis[r];
    float l = dr * (pr[t] + dr * h2[r]) + b2[0];
    __syncthreads();
    float pn = s_pn;
    red[t] = (t == 0) ? fmaxf(l, pn) : l;
    __syncthreads();
    for (int sft = 512; sft > 0; sft >>= 1) {
        if (t < sft) red[t] = fmaxf(red[t], red[t + sft]);
        __syncthreads();
    }
    if (t == 0) s_max = red[0];
    __syncthreads();
    float m = s_max;
    float el = expf(l - m);
    red[t] = el + ((t == 0) ? expf(pn - m) : 0.f);
    __syncthreads();
    for (int sft = 512; sft > 0; sft >>= 1) {
        if (t < sft) red[t] += red[t + sft];
        __syncthreads();
    }
    if (t == 0) s_sum = red[0];
    __syncthreads();
    float inv = 1.0f / s_sum;
    out[t] = el * inv;
    if (t == 0) {
        out[K_] = expf(pn - m) * inv;   // prob_nothing slot
        out[K_ + 1] = s_v;              // v
    }
}

extern "C" void kernel_launch(void* const* d_in, const int* in_sizes, int n_in,
                              void* d_out, int out_size, void* d_ws, size_t ws_size,
                              hipStream_t stream) {
    const float* x    = (const float*)d_in[0];
    const int*   ei   = (const int*)d_in[1];
    const int*   src  = ei;
    const int*   dst  = ei + E_;
    const int*   ready= (const int*)d_in[2];
    const float* W1   = (const float*)d_in[3];
    const float* b1   = (const float*)d_in[4];
    const float* W2   = (const float*)d_in[5];
    const float* b2   = (const float*)d_in[6];
    const float* Wd   = (const float*)d_in[7];
    const float* bd   = (const float*)d_in[8];
    const float* Wv   = (const float*)d_in[9];
    const float* bv   = (const float*)d_in[10];
    float* out = (float*)d_out;

    char* ws = (char*)d_ws;
    size_t o = 0;
    int*   cnt      = (int*)(ws + o);    o += align512(N_ * sizeof(int));
    int*   rank     = (int*)(ws + o);    o += align512((size_t)E_ * sizeof(int));
    int*   rowstart = (int*)(ws + o);    o += align512((N_ + 1) * sizeof(int));
    int*   nbr      = (int*)(ws + o);    o += align512((size_t)E_ * sizeof(int));
    float* x12      = (float*)(ws + o);  o += align512((size_t)N_ * 12 * sizeof(float));
    float* dis      = (float*)(ws + o);  o += align512(N_ * sizeof(float));
    float* h2       = (float*)(ws + o);  o += align512(N_ * sizeof(float));
    float* pr       = (float*)(ws + o);  o += align512(K_ * sizeof(float));
    float* xmean    = (float*)(ws + o);  o += align512(64 * sizeof(float));

    const int B = 256;
    int g_edge = (E_ + B - 1) / B;
    int g_node = (N_ + B - 1) / B;
    int g_pad  = (N_ * 12 + B - 1) / B;

    k_init   <<<g_node, B, 0, stream>>>(cnt, xmean);
    k_cnt    <<<g_edge, B, 0, stream>>>(src, cnt, rank);
    k_scan   <<<1, 1024, 0, stream>>>(cnt, rowstart, dis);
    k_scatter<<<g_edge, B, 0, stream>>>(src, dst, rank, rowstart, nbr);
    k_pad    <<<g_pad, B, 0, stream>>>(x, x12);
    k_node   <<<g_node, B, 0, stream>>>(x12, nbr, rowstart, dis, W1, b1, W2, h2, xmean);
    k_ready  <<<K_, 64, 0, stream>>>(ready, rowstart, nbr, dis, h2, pr);
    k_final  <<<1, 1024, 0, stream>>>(ready, dis, h2, pr, xmean,
                                      b2, Wd, bd, Wv, bv, out);
}

// Round 3
// 615.838 us; speedup vs baseline: 3.3557x; 1.0125x over previous
//
#include <hip/hip_runtime.h>
#include <math.h>

#define N_ 100000
#define E_ 3200000
#define K_ 1024
#define D_ 11
#define N4_ (N_ / 4)          // 25000 int4s of cnt
#define NB_ 98                // ceil(N4_/256) scan blocks

static inline size_t align512(size_t x) { return (x + 511) & ~(size_t)511; }

// ---------------- init: zero counters ----------------
__global__ void k_init(int* __restrict__ cnt, float* __restrict__ xmean) {
    int i = blockIdx.x * blockDim.x + threadIdx.x;
    if (i < N_) cnt[i] = 0;
    if (i < 64) xmean[i] = 0.f;
}

// ---------------- count out-degree at src (vectorized, no rank) -------------
__global__ void k_cnt(const int* __restrict__ src, int* __restrict__ cnt) {
    int e4 = blockIdx.x * blockDim.x + threadIdx.x;
    if (e4 >= E_ / 4) return;
    int4 s = ((const int4*)src)[e4];
    atomicAdd(&cnt[s.x], 1);
    atomicAdd(&cnt[s.y], 1);
    atomicAdd(&cnt[s.z], 1);
    atomicAdd(&cnt[s.w], 1);
}

// ---------------- scan phase 1: per-block sums of cnt ----------------
__global__ __launch_bounds__(256) void k_bsum(const int* __restrict__ cnt,
                                              int* __restrict__ bsum) {
    __shared__ int red[256];
    int t = threadIdx.x;
    int i4 = blockIdx.x * 256 + t;
    int4 c = (i4 < N4_) ? ((const int4*)cnt)[i4] : make_int4(0, 0, 0, 0);
    red[t] = c.x + c.y + c.z + c.w;
    __syncthreads();
    for (int off = 128; off > 0; off >>= 1) {
        if (t < off) red[t] += red[t + off];
        __syncthreads();
    }
    if (t == 0) bsum[blockIdx.x] = red[0];
}

// ---------------- scan phase 2: scan the 98 block sums ----------------
__global__ __launch_bounds__(128) void k_bscan(const int* __restrict__ bsum,
                                               int* __restrict__ boff,
                                               int* __restrict__ rowstart) {
    __shared__ int s[128];
    int t = threadIdx.x;
    s[t] = (t < NB_) ? bsum[t] : 0;
    __syncthreads();
    for (int off = 1; off < 128; off <<= 1) {
        int v = (t >= off) ? s[t - off] : 0;
        __syncthreads();
        s[t] += v;
        __syncthreads();
    }
    if (t < NB_) boff[t] = (t > 0) ? s[t - 1] : 0;  // exclusive
    if (t == 127) rowstart[N_] = s[127];            // total = E_
}

// ---------------- scan phase 3: rowstart/cursor/dis + pack dis into x16 -----
__global__ __launch_bounds__(256) void k_row(const int* __restrict__ cnt,
                                             const int* __restrict__ boff,
                                             int* __restrict__ rowstart,
                                             int* __restrict__ cursor,
                                             float* __restrict__ dis,
                                             float* __restrict__ x16) {
    __shared__ int s[256];
    int b = blockIdx.x, t = threadIdx.x;
    int i4 = b * 256 + t;
    int4 c = (i4 < N4_) ? ((const int4*)cnt)[i4] : make_int4(0, 0, 0, 0);
    s[t] = c.x + c.y + c.z + c.w;
    __syncthreads();
    for (int off = 1; off < 256; off <<= 1) {
        int v = (t >= off) ? s[t - off] : 0;
        __syncthreads();
        s[t] += v;
        __syncthreads();
    }
    if (i4 >= N4_) return;
    int base = boff[b] + ((t > 0) ? s[t - 1] : 0);
    int r0 = base, r1 = r0 + c.x, r2 = r1 + c.y, r3 = r2 + c.z;
    ((int4*)rowstart)[i4] = make_int4(r0, r1, r2, r3);
    ((int4*)cursor)[i4]   = make_int4(r0, r1, r2, r3);
    float d0 = rsqrtf((float)(c.x + 1));
    float d1 = rsqrtf((float)(c.y + 1));
    float d2 = rsqrtf((float)(c.z + 1));
    float d3 = rsqrtf((float)(c.w + 1));
    ((float4*)dis)[i4] = make_float4(d0, d1, d2, d3);
    int i = i4 * 4;
    x16[(size_t)(i + 0) * 16 + 11] = d0;
    x16[(size_t)(i + 1) * 16 + 11] = d1;
    x16[(size_t)(i + 2) * 16 + 11] = d2;
    x16[(size_t)(i + 3) * 16 + 11] = d3;
}

// ---------------- pad x [N,11] -> x16 [N,16] (slot 11 left for dis) ---------
__global__ void k_pad(const float* __restrict__ x, float* __restrict__ x16) {
    int i = blockIdx.x * blockDim.x + threadIdx.x;
    if (i >= N_ * 16) return;
    int n = i >> 4, j = i & 15;
    if (j < D_)       x16[i] = x[n * D_ + j];
    else if (j >= 12) x16[i] = 0.f;
    // j == 11: dis slot, written by k_row
}

// ---------------- scatter dst into CSR slots via cursor atomics -------------
__global__ void k_scatter(const int* __restrict__ src, const int* __restrict__ dst,
                          int* __restrict__ cursor, int* __restrict__ nbr) {
    int e4 = blockIdx.x * blockDim.x + threadIdx.x;
    if (e4 >= E_ / 4) return;
    int4 s = ((const int4*)src)[e4];
    int4 d = ((const int4*)dst)[e4];
    nbr[atomicAdd(&cursor[s.x], 1)] = d.x;
    nbr[atomicAdd(&cursor[s.y], 1)] = d.y;
    nbr[atomicAdd(&cursor[s.z], 1)] = d.z;
    nbr[atomicAdd(&cursor[s.w], 1)] = d.w;
}

// ---------------- per-node: gather-agg + xW1+b1, relu, hd=dis*[h,x]@W2, mean(h)
__global__ __launch_bounds__(256) void k_node(
    const float* __restrict__ x16, const int* __restrict__ nbr,
    const int* __restrict__ rowstart,
    const float* __restrict__ W1, const float* __restrict__ b1,
    const float* __restrict__ W2,
    float* __restrict__ hd, float* __restrict__ xmean) {
    __shared__ float sW1[D_ * 64];
    __shared__ float sb1[64];
    __shared__ float sW2[75];
    __shared__ float smean[64];
    int t = threadIdx.x;
    for (int k = t; k < D_ * 64; k += 256) sW1[k] = W1[k];
    if (t < 64) { sb1[t] = b1[t]; smean[t] = 0.f; }
    if (t < 75) sW2[t] = W2[t];
    __syncthreads();

    int i = blockIdx.x * 256 + t;
    if (i < N_) {
        int base = rowstart[i], end = rowstart[i + 1];
        float acc[D_];
#pragma unroll
        for (int j = 0; j < D_; j++) acc[j] = 0.f;
        for (int p = base; p < end; p++) {
            int d = nbr[p];
            const float4* xr = (const float4*)(x16 + (size_t)d * 16);
            float4 a0 = xr[0], a1 = xr[1], a2 = xr[2];
            float w = a2.w;  // dis[d] packed in slot 11
            acc[0] = fmaf(w, a0.x, acc[0]);
            acc[1] = fmaf(w, a0.y, acc[1]);
            acc[2] = fmaf(w, a0.z, acc[2]);
            acc[3] = fmaf(w, a0.w, acc[3]);
            acc[4] = fmaf(w, a1.x, acc[4]);
            acc[5] = fmaf(w, a1.y, acc[5]);
            acc[6] = fmaf(w, a1.z, acc[6]);
            acc[7] = fmaf(w, a1.w, acc[7]);
            acc[8] = fmaf(w, a2.x, acc[8]);
            acc[9] = fmaf(w, a2.y, acc[9]);
            acc[10] = fmaf(w, a2.z, acc[10]);
        }
        const float4* xs = (const float4*)(x16 + (size_t)i * 16);
        float4 s0 = xs[0], s1 = xs[1], s2 = xs[2];
        float di = s2.w;
        float xr_[D_], g[D_];
        xr_[0]=s0.x; xr_[1]=s0.y; xr_[2]=s0.z; xr_[3]=s0.w;
        xr_[4]=s1.x; xr_[5]=s1.y; xr_[6]=s1.z; xr_[7]=s1.w;
        xr_[8]=s2.x; xr_[9]=s2.y; xr_[10]=s2.z;
#pragma unroll
        for (int j = 0; j < D_; j++) g[j] = di * (acc[j] + di * xr_[j]);

        float h2v = 0.f;
        int f0 = t & 63;  // lane-stagger: no same-address LDS atomic collisions
#pragma unroll 8
        for (int k = 0; k < 64; k++) {
            int f = (f0 + k) & 63;
            float a = sb1[f];
#pragma unroll
            for (int j = 0; j < D_; j++) a = fmaf(g[j], sW1[j * 64 + f], a);
            float hf = fmaxf(a, 0.f);
            atomicAdd(&smean[f], hf);
            h2v = fmaf(hf, sW2[f], h2v);
        }
#pragma unroll
        for (int j = 0; j < D_; j++) h2v = fmaf(xr_[j], sW2[64 + j], h2v);
        hd[i] = di * h2v;  // pre-scaled: conv2 needs dis[d]*h2[d]
    }
    __syncthreads();
    if (t < 64) atomicAdd(&xmean[t], smean[t]);
}

// ---------------- conv2 gather at ready nodes only (1 wave per node) --------
__global__ __launch_bounds__(64) void k_ready(
    const int* __restrict__ ready, const int* __restrict__ rowstart,
    const int* __restrict__ nbr, const float* __restrict__ hd,
    float* __restrict__ pr) {
    int b = blockIdx.x;
    int r = ready[b];
    int base = rowstart[r], end = rowstart[r + 1];
    float s = 0.f;
    for (int p = base + threadIdx.x; p < end; p += 64) s += hd[nbr[p]];
#pragma unroll
    for (int off = 32; off > 0; off >>= 1) s += __shfl_down(s, off);
    if (threadIdx.x == 0) pr[b] = s;
}

// ---------------- finalize: logits, prob_nothing, v, softmax ----------------
__global__ __launch_bounds__(1024) void k_final(
    const int* __restrict__ ready, const float* __restrict__ dis,
    const float* __restrict__ hd, const float* __restrict__ pr,
    const float* __restrict__ xmean,
    const float* __restrict__ b2,
    const float* __restrict__ Wd, const float* __restrict__ bd,
    const float* __restrict__ Wv, const float* __restrict__ bv,
    float* __restrict__ out) {
    __shared__ float xm[64];
    __shared__ float red[1024];
    __shared__ float s_max, s_sum, s_pn, s_v;
    int t = threadIdx.x;
    if (t < 64) xm[t] = xmean[t] * (1.0f / N_);
    __syncthreads();
    if (t == 0) {
        float pn = bd[0], vv = bv[0];
        for (int f = 0; f < 64; f++) { pn += xm[f] * Wd[f]; vv += xm[f] * Wv[f]; }
        s_pn = pn; s_v = vv;
    }
    int r = ready[t];
    float dr = dis[r];
    float l = dr * (pr[t] + hd[r]) + b2[0];   // dr*pr + dr^2*h2  (hd = dr*h2)
    __syncthreads();
    float pn = s_pn;
    red[t] = (t == 0) ? fmaxf(l, pn) : l;
    __syncthreads();
    for (int sft = 512; sft > 0; sft >>= 1) {
        if (t < sft) red[t] = fmaxf(red[t], red[t + sft]);
        __syncthreads();
    }
    if (t == 0) s_max = red[0];
    __syncthreads();
    float m = s_max;
    float el = expf(l - m);
    red[t] = el + ((t == 0) ? expf(pn - m) : 0.f);
    __syncthreads();
    for (int sft = 512; sft > 0; sft >>= 1) {
        if (t < sft) red[t] += red[t + sft];
        __syncthreads();
    }
    if (t == 0) s_sum = red[0];
    __syncthreads();
    float inv = 1.0f / s_sum;
    out[t] = el * inv;
    if (t == 0) {
        out[K_] = expf(pn - m) * inv;   // prob_nothing slot
        out[K_ + 1] = s_v;              // v
    }
}

extern "C" void kernel_launch(void* const* d_in, const int* in_sizes, int n_in,
                              void* d_out, int out_size, void* d_ws, size_t ws_size,
                              hipStream_t stream) {
    const float* x    = (const float*)d_in[0];
    const int*   ei   = (const int*)d_in[1];
    const int*   src  = ei;
    const int*   dst  = ei + E_;
    const int*   ready= (const int*)d_in[2];
    const float* W1   = (const float*)d_in[3];
    const float* b1   = (const float*)d_in[4];
    const float* W2   = (const float*)d_in[5];
    const float* b2   = (const float*)d_in[6];
    const float* Wd   = (const float*)d_in[7];
    const float* bd   = (const float*)d_in[8];
    const float* Wv   = (const float*)d_in[9];
    const float* bv   = (const float*)d_in[10];
    float* out = (float*)d_out;

    char* ws = (char*)d_ws;
    size_t o = 0;
    int*   cnt      = (int*)(ws + o);    o += align512(N_ * sizeof(int));
    int*   rowstart = (int*)(ws + o);    o += align512((N_ + 4) * sizeof(int));
    int*   cursor   = (int*)(ws + o);    o += align512((N_ + 4) * sizeof(int));
    int*   nbr      = (int*)(ws + o);    o += align512((size_t)E_ * sizeof(int));
    float* x16      = (float*)(ws + o);  o += align512((size_t)N_ * 16 * sizeof(float));
    float* dis      = (float*)(ws + o);  o += align512(N_ * sizeof(float));
    float* hd       = (float*)(ws + o);  o += align512(N_ * sizeof(float));
    float* pr       = (float*)(ws + o);  o += align512(K_ * sizeof(float));
    float* xmean    = (float*)(ws + o);  o += align512(64 * sizeof(float));
    int*   bsum     = (int*)(ws + o);    o += align512(NB_ * sizeof(int));
    int*   boff     = (int*)(ws + o);    o += align512(NB_ * sizeof(int));

    const int B = 256;
    int g_e4   = (E_ / 4 + B - 1) / B;
    int g_node = (N_ + B - 1) / B;
    int g_pad  = (N_ * 16 + B - 1) / B;

    k_init   <<<g_node, B, 0, stream>>>(cnt, xmean);
    k_cnt    <<<g_e4, B, 0, stream>>>(src, cnt);
    k_bsum   <<<NB_, B, 0, stream>>>(cnt, bsum);
    k_bscan  <<<1, 128, 0, stream>>>(bsum, boff, rowstart);
    k_row    <<<NB_, B, 0, stream>>>(cnt, boff, rowstart, cursor, dis, x16);
    k_pad    <<<g_pad, B, 0, stream>>>(x, x16);
    k_scatter<<<g_e4, B, 0, stream>>>(src, dst, cursor, nbr);
    k_node   <<<g_node, B, 0, stream>>>(x16, nbr, rowstart, W1, b1, W2, hd, xmean);
    k_ready  <<<K_, 64, 0, stream>>>(ready, rowstart, nbr, hd, pr);
    k_final  <<<1, 1024, 0, stream>>>(ready, dis, hd, pr, xmean,
                                      b2, Wd, bd, Wv, bv, out);
}

// Round 4
// 521.506 us; speedup vs baseline: 3.9626x; 1.1809x over previous
//
#include <hip/hip_runtime.h>
#include <math.h>

#define N_ 100000
#define E_ 3200000
#define K_ 1024
#define D_ 11
#define NBUCK_ 391            // ceil(N/256) buckets of 256 nodes (by src>>8)
#define CAPB_ 16384           // global slots per bucket (mean fill ~8192)
#define CAP_ 32               // LDS staging slots per bucket
#define GB_ 256               // binning blocks
#define CHUNK_ (E_ / GB_)     // 12500 edges per binning block

static inline size_t align512(size_t x) { return (x + 511) & ~(size_t)511; }

// ---------------- init: zero flag/xmean, seed bucket cursors ----------------
__global__ void k_init(unsigned char* __restrict__ flag, float* __restrict__ xmean,
                       int* __restrict__ bcur) {
    int i = blockIdx.x * blockDim.x + threadIdx.x;
    if (i < N_) flag[i] = 0;
    if (i < 64) xmean[i] = 0.f;
    if (i < NBUCK_) bcur[i] = i * CAPB_;
}

__global__ void k_flags(const int* __restrict__ ready, unsigned char* __restrict__ flag) {
    int i = blockIdx.x * blockDim.x + threadIdx.x;
    if (i < K_) flag[ready[i]] = 1;
}

// ---------------- pad x [N,11] -> x16 [N,16] (slot 11 = dis, by k_deg) ------
__global__ void k_pad(const float* __restrict__ x, float* __restrict__ x16) {
    int i = blockIdx.x * blockDim.x + threadIdx.x;
    if (i >= N_ * 16) return;
    int n = i >> 4, j = i & 15;
    if (j < D_)       x16[i] = x[n * D_ + j];
    else if (j >= 12) x16[i] = 0.f;
}

// ---------------- bucket partition with LDS write-combining -----------------
// pack = (src&255)<<17 | dst   (dst < 2^17, srclow 8 bits)
__global__ __launch_bounds__(256) void k_bin(const int* __restrict__ src,
                                             const int* __restrict__ dst,
                                             int* __restrict__ bcur,
                                             int* __restrict__ gbuf) {
    __shared__ int sbuf[NBUCK_][CAP_];   // ~50 KB
    __shared__ int scnt[NBUCK_];
    int t = threadIdx.x;
    for (int b = t; b < NBUCK_; b += 256) scnt[b] = 0;
    __syncthreads();
    int e0 = blockIdx.x * CHUNK_;
    for (int base = 0; base < CHUNK_; base += 256) {
        int idx = base + t;
        if (idx < CHUNK_) {
            int e = e0 + idx;
            int s = src[e], d = dst[e];
            int b = s >> 8;
            int pack = ((s & 255) << 17) | d;
            int pos = atomicAdd(&scnt[b], 1);
            if (pos < CAP_) sbuf[b][pos] = pack;
            else gbuf[atomicAdd(&bcur[b], 1)] = pack;  // p ~ 1e-20 fallback
        }
        __syncthreads();
        // flush full 64B lines (16 packed edges) per hot bucket
        for (int b = t; b < NBUCK_; b += 256) {
            int c = scnt[b];
            if (c > CAP_) c = CAP_;
            while (c >= 16) {
                int g = atomicAdd(&bcur[b], 16);
                c -= 16;
#pragma unroll
                for (int k = 0; k < 16; k++) gbuf[g + k] = sbuf[b][c + k];
            }
            scnt[b] = c;
        }
        __syncthreads();
    }
    // final partial flush (contiguous runs, still line-friendly)
    for (int b = t; b < NBUCK_; b += 256) {
        int c = scnt[b];
        if (c > CAP_) c = CAP_;
        if (c > 0) {
            int g = atomicAdd(&bcur[b], c);
            for (int k = 0; k < c; k++) gbuf[g + k] = sbuf[b][k];
        }
    }
}

// ---------------- per-bucket degree count -> dis (packed into x16) ----------
__global__ __launch_bounds__(256) void k_deg(const int* __restrict__ bcur,
                                             const int* __restrict__ gbuf,
                                             float* __restrict__ dis,
                                             float* __restrict__ x16) {
    __shared__ int hist[256];
    int t = threadIdx.x, b = blockIdx.x;
    hist[t] = 0;
    __syncthreads();
    int base = b * CAPB_, cnt = bcur[b] - base;
    for (int p = t; p < cnt; p += 256) atomicAdd(&hist[gbuf[base + p] >> 17], 1);
    __syncthreads();
    int node = (b << 8) + t;
    if (node < N_) {
        float dv = rsqrtf((float)(hist[t] + 1));  // +1 self-loop
        dis[node] = dv;
        x16[(size_t)node * 16 + 11] = dv;
    }
}

// ---------------- per-bucket: aggregate + full node transform (fused) -------
__global__ __launch_bounds__(256) void k_agg(const int* __restrict__ bcur,
                                             const int* __restrict__ gbuf,
                                             const float* __restrict__ x16,
                                             const float* __restrict__ W1,
                                             const float* __restrict__ b1,
                                             const float* __restrict__ W2,
                                             float* __restrict__ hd,
                                             float* __restrict__ xmean) {
    __shared__ float uloc[256 * D_];     // [srclow*11 + j], 11 KB
    __shared__ float sW1[D_ * 64];
    __shared__ float sb1[64];
    __shared__ float sW2[75];
    __shared__ float smean[64];
    int t = threadIdx.x, b = blockIdx.x;
    for (int k = t; k < 256 * D_; k += 256) uloc[k] = 0.f;
    for (int k = t; k < D_ * 64; k += 256) sW1[k] = W1[k];
    if (t < 64) { sb1[t] = b1[t]; smean[t] = 0.f; }
    if (t < 75) sW2[t] = W2[t];
    __syncthreads();

    int base = b * CAPB_, cnt = bcur[b] - base;
    for (int p = t; p < cnt; p += 256) {
        int pack = gbuf[base + p];
        int sl = pack >> 17, d = pack & 131071;
        const float4* xr = (const float4*)(x16 + (size_t)d * 16);
        float4 a0 = xr[0], a1 = xr[1], a2 = xr[2];
        float w = a2.w;  // dis[d]
        float* u = uloc + sl * D_;
        atomicAdd(&u[0],  w * a0.x);
        atomicAdd(&u[1],  w * a0.y);
        atomicAdd(&u[2],  w * a0.z);
        atomicAdd(&u[3],  w * a0.w);
        atomicAdd(&u[4],  w * a1.x);
        atomicAdd(&u[5],  w * a1.y);
        atomicAdd(&u[6],  w * a1.z);
        atomicAdd(&u[7],  w * a1.w);
        atomicAdd(&u[8],  w * a2.x);
        atomicAdd(&u[9],  w * a2.y);
        atomicAdd(&u[10], w * a2.z);
    }
    __syncthreads();

    int node = (b << 8) + t;
    if (node < N_) {
        const float4* xs = (const float4*)(x16 + (size_t)node * 16);
        float4 s0 = xs[0], s1 = xs[1], s2 = xs[2];
        float di = s2.w;
        float xr_[D_], g[D_];
        xr_[0]=s0.x; xr_[1]=s0.y; xr_[2]=s0.z; xr_[3]=s0.w;
        xr_[4]=s1.x; xr_[5]=s1.y; xr_[6]=s1.z; xr_[7]=s1.w;
        xr_[8]=s2.x; xr_[9]=s2.y; xr_[10]=s2.z;
#pragma unroll
        for (int j = 0; j < D_; j++) g[j] = di * (uloc[t * D_ + j] + di * xr_[j]);

        float h2v = 0.f;
        int f0 = t & 63;  // lane-stagger: no same-address LDS atomic collisions
#pragma unroll 8
        for (int k = 0; k < 64; k++) {
            int f = (f0 + k) & 63;
            float a = sb1[f];
#pragma unroll
            for (int j = 0; j < D_; j++) a = fmaf(g[j], sW1[j * 64 + f], a);
            float hf = fmaxf(a, 0.f);
            atomicAdd(&smean[f], hf);
            h2v = fmaf(hf, sW2[f], h2v);
        }
#pragma unroll
        for (int j = 0; j < D_; j++) h2v = fmaf(xr_[j], sW2[64 + j], h2v);
        hd[node] = di * h2v;  // pre-scaled: conv2 needs dis[d]*h2[d]
    }
    __syncthreads();
    if (t < 64) atomicAdd(&xmean[t], smean[t]);
}

// ---------------- per-bucket conv2: flag-gated accumulate of hd[dst] --------
__global__ __launch_bounds__(256) void k_pr(const int* __restrict__ bcur,
                                            const int* __restrict__ gbuf,
                                            const unsigned char* __restrict__ flag,
                                            const float* __restrict__ hd,
                                            float* __restrict__ pr_raw) {
    __shared__ float prl[256];
    __shared__ unsigned char fl[256];
    int t = threadIdx.x, b = blockIdx.x;
    prl[t] = 0.f;
    int node = (b << 8) + t;
    fl[t] = (node < N_) ? flag[node] : 0;
    __syncthreads();
    int base = b * CAPB_, cnt = bcur[b] - base;
    for (int p = t; p < cnt; p += 256) {
        int pack = gbuf[base + p];
        int sl = pack >> 17;
        if (fl[sl]) atomicAdd(&prl[sl], hd[pack & 131071]);
    }
    __syncthreads();
    if (node < N_ && fl[t]) pr_raw[node] = prl[t];
}

// ---------------- finalize: logits, prob_nothing, v, softmax ----------------
__global__ __launch_bounds__(1024) void k_final(
    const int* __restrict__ ready, const float* __restrict__ dis,
    const float* __restrict__ hd, const float* __restrict__ pr_raw,
    const float* __restrict__ xmean,
    const float* __restrict__ b2,
    const float* __restrict__ Wd, const float* __restrict__ bd,
    const float* __restrict__ Wv, const float* __restrict__ bv,
    float* __restrict__ out) {
    __shared__ float xm[64];
    __shared__ float red[1024];
    __shared__ float s_max, s_sum, s_pn, s_v;
    int t = threadIdx.x;
    if (t < 64) xm[t] = xmean[t] * (1.0f / N_);
    __syncthreads();
    if (t == 0) {
        float pn = bd[0], vv = bv[0];
        for (int f = 0; f < 64; f++) { pn += xm[f] * Wd[f]; vv += xm[f] * Wv[f]; }
        s_pn = pn; s_v = vv;
    }
    int r = ready[t];
    float dr = dis[r];
    float l = dr * (pr_raw[r] + hd[r]) + b2[0];   // dr*Σhd[d] + dr²h2[r] + b2
    __syncthreads();
    float pn = s_pn;
    red[t] = (t == 0) ? fmaxf(l, pn) : l;
    __syncthreads();
    for (int sft = 512; sft > 0; sft >>= 1) {
        if (t < sft) red[t] = fmaxf(red[t], red[t + sft]);
        __syncthreads();
    }
    if (t == 0) s_max = red[0];
    __syncthreads();
    float m = s_max;
    float el = expf(l - m);
    red[t] = el + ((t == 0) ? expf(pn - m) : 0.f);
    __syncthreads();
    for (int sft = 512; sft > 0; sft >>= 1) {
        if (t < sft) red[t] += red[t + sft];
        __syncthreads();
    }
    if (t == 0) s_sum = red[0];
    __syncthreads();
    float inv = 1.0f / s_sum;
    out[t] = el * inv;
    if (t == 0) {
        out[K_] = expf(pn - m) * inv;   // prob_nothing slot
        out[K_ + 1] = s_v;              // v
    }
}

extern "C" void kernel_launch(void* const* d_in, const int* in_sizes, int n_in,
                              void* d_out, int out_size, void* d_ws, size_t ws_size,
                              hipStream_t stream) {
    const float* x    = (const float*)d_in[0];
    const int*   ei   = (const int*)d_in[1];
    const int*   src  = ei;
    const int*   dst  = ei + E_;
    const int*   ready= (const int*)d_in[2];
    const float* W1   = (const float*)d_in[3];
    const float* b1   = (const float*)d_in[4];
    const float* W2   = (const float*)d_in[5];
    const float* b2   = (const float*)d_in[6];
    const float* Wd   = (const float*)d_in[7];
    const float* bd   = (const float*)d_in[8];
    const float* Wv   = (const float*)d_in[9];
    const float* bv   = (const float*)d_in[10];
    float* out = (float*)d_out;

    char* ws = (char*)d_ws;
    size_t o = 0;
    int*   bcur   = (int*)(ws + o);          o += align512(NBUCK_ * sizeof(int));
    int*   gbuf   = (int*)(ws + o);          o += align512((size_t)NBUCK_ * CAPB_ * sizeof(int));
    float* x16    = (float*)(ws + o);        o += align512((size_t)N_ * 16 * sizeof(float));
    float* dis    = (float*)(ws + o);        o += align512(N_ * sizeof(float));
    float* hd     = (float*)(ws + o);        o += align512(N_ * sizeof(float));
    float* pr_raw = (float*)(ws + o);        o += align512(N_ * sizeof(float));
    unsigned char* flag = (unsigned char*)(ws + o); o += align512(N_);
    float* xmean  = (float*)(ws + o);        o += align512(64 * sizeof(float));

    const int B = 256;
    int g_node = (N_ + B - 1) / B;
    int g_pad  = (N_ * 16 + B - 1) / B;

    k_init <<<g_node, B, 0, stream>>>(flag, xmean, bcur);
    k_flags<<<(K_ + B - 1) / B, B, 0, stream>>>(ready, flag);
    k_pad  <<<g_pad, B, 0, stream>>>(x, x16);
    k_bin  <<<GB_, B, 0, stream>>>(src, dst, bcur, gbuf);
    k_deg  <<<NBUCK_, B, 0, stream>>>(bcur, gbuf, dis, x16);
    k_agg  <<<NBUCK_, B, 0, stream>>>(bcur, gbuf, x16, W1, b1, W2, hd, xmean);
    k_pr   <<<NBUCK_, B, 0, stream>>>(bcur, gbuf, flag, hd, pr_raw);
    k_final<<<1, 1024, 0, stream>>>(ready, dis, hd, pr_raw, xmean,
                                    b2, Wd, bd, Wv, bv, out);
}

// Round 5
// 489.203 us; speedup vs baseline: 4.2243x; 1.0660x over previous
//
#include <hip/hip_runtime.h>
#include <math.h>

#define N_ 100000
#define E_ 3200000
#define K_ 1024
#define D_ 11
#define NBUCK_ 391            // ceil(N/256) buckets of 256 nodes (by src>>8)
#define NPAD_ (NBUCK_ * 256)  // 100096 padded node count
#define CAPB_ 16384           // global slots per bucket (mean fill ~8184)
#define CAP_ 16               // LDS staging slots per bucket (one 64B line)
#define GB_ 512               // binning blocks
#define CHUNK_ (E_ / GB_)     // 6250 edges per binning block
#define S_ 4                  // segments per bucket for edge-parallel kernels

static inline size_t align512(size_t x) { return (x + 511) & ~(size_t)511; }

// ---------------- init: zero deg/pr_raw/flag/xmean, seed bucket cursors -----
__global__ void k_init(int* __restrict__ deg, float* __restrict__ pr_raw,
                       unsigned char* __restrict__ flag, float* __restrict__ xmean,
                       int* __restrict__ bcur) {
    int i = blockIdx.x * blockDim.x + threadIdx.x;
    if (i < N_) { deg[i] = 0; pr_raw[i] = 0.f; flag[i] = 0; }
    if (i < 64) xmean[i] = 0.f;
    if (i < NBUCK_) bcur[i] = i * CAPB_;
}

__global__ void k_flags(const int* __restrict__ ready, unsigned char* __restrict__ flag) {
    int i = blockIdx.x * blockDim.x + threadIdx.x;
    if (i < K_) flag[ready[i]] = 1;
}

// ---------------- pad x [N,11] -> x16 [N,16] (slot 11 = dis, by k_dis) ------
__global__ void k_pad(const float* __restrict__ x, float* __restrict__ x16) {
    int i = blockIdx.x * blockDim.x + threadIdx.x;
    if (i >= N_ * 16) return;
    int n = i >> 4, j = i & 15;
    if (j < D_)       x16[i] = x[n * D_ + j];
    else if (j >= 12) x16[i] = 0.f;
}

// ---------------- bucket partition with LDS write-combining -----------------
// pack = (src&255)<<17 | dst   (dst < 2^17, srclow 8 bits)
__global__ __launch_bounds__(256) void k_bin(const int* __restrict__ src,
                                             const int* __restrict__ dst,
                                             int* __restrict__ bcur,
                                             int* __restrict__ gbuf) {
    __shared__ int sbuf[NBUCK_][CAP_];   // ~25 KB
    __shared__ int scnt[NBUCK_];
    int t = threadIdx.x;
    for (int b = t; b < NBUCK_; b += 256) scnt[b] = 0;
    __syncthreads();
    int e0 = blockIdx.x * CHUNK_;
    for (int base = 0; base < CHUNK_; base += 512) {
#pragma unroll
        for (int q = 0; q < 2; q++) {
            int idx = base + q * 256 + t;
            if (idx < CHUNK_) {
                int e = e0 + idx;
                int s = src[e], d = dst[e];
                int b = s >> 8;
                int pack = ((s & 255) << 17) | d;
                int pos = atomicAdd(&scnt[b], 1);
                if (pos < CAP_) sbuf[b][pos] = pack;
                else gbuf[atomicAdd(&bcur[b], 1)] = pack;  // ~never
            }
        }
        __syncthreads();
        for (int b = t; b < NBUCK_; b += 256) {
            if (scnt[b] >= CAP_) {   // exactly one full 64B line
                int g = atomicAdd(&bcur[b], 16);
                if ((g & 3) == 0) {
                    int4* gp = (int4*)(gbuf + g);
                    const int4* sp = (const int4*)sbuf[b];
                    gp[0] = sp[0]; gp[1] = sp[1]; gp[2] = sp[2]; gp[3] = sp[3];
                } else {
                    for (int k = 0; k < 16; k++) gbuf[g + k] = sbuf[b][k];
                }
                scnt[b] = 0;
            }
        }
        __syncthreads();
    }
    // final partial flush
    for (int b = t; b < NBUCK_; b += 256) {
        int c = scnt[b];
        if (c > CAP_) c = CAP_;
        if (c > 0) {
            int g = atomicAdd(&bcur[b], c);
            for (int k = 0; k < c; k++) gbuf[g + k] = sbuf[b][k];
        }
    }
}

// ---------------- per-bucket-segment degree hist -> coalesced atomic flush --
__global__ __launch_bounds__(256) void k_deg(const int* __restrict__ bcur,
                                             const int* __restrict__ gbuf,
                                             int* __restrict__ deg) {
    __shared__ int hist[256];
    int t = threadIdx.x, b = blockIdx.x, s = blockIdx.y;
    hist[t] = 0;
    __syncthreads();
    int base = b * CAPB_, cnt = bcur[b] - base;
    int seg = (cnt + S_ - 1) / S_;
    int lo = s * seg, hi = min(lo + seg, cnt);
    for (int p = lo + t; p < hi; p += 256)
        atomicAdd(&hist[gbuf[base + p] >> 17], 1);
    __syncthreads();
    int node = (b << 8) + t;
    if (node < N_ && hist[t]) atomicAdd(&deg[node], hist[t]);
}

// ---------------- dis = rsqrt(deg+1), packed into x16 slot 11 ---------------
__global__ void k_dis(const int* __restrict__ deg, float* __restrict__ dis,
                      float* __restrict__ x16) {
    int i = blockIdx.x * blockDim.x + threadIdx.x;
    if (i >= N_) return;
    float dv = rsqrtf((float)(deg[i] + 1));
    dis[i] = dv;
    x16[(size_t)i * 16 + 11] = dv;
}

// ---------------- per-bucket-segment aggregate -> non-atomic partial slices -
__global__ __launch_bounds__(256) void k_agg(const int* __restrict__ bcur,
                                             const int* __restrict__ gbuf,
                                             const float* __restrict__ x16,
                                             float* __restrict__ upart) {
    __shared__ float uloc[256 * 13];   // stride 13: coprime w/ 32 banks
    int t = threadIdx.x, b = blockIdx.x, s = blockIdx.y;
    for (int k = t; k < 256 * 13; k += 256) uloc[k] = 0.f;
    __syncthreads();
    int base = b * CAPB_, cnt = bcur[b] - base;
    int seg = (cnt + S_ - 1) / S_;
    int lo = s * seg, hi = min(lo + seg, cnt);
    int p = lo + t;
    for (; p + 768 < hi; p += 1024) {   // 4-edge ILP batch
        int pk[4];
        pk[0] = gbuf[base + p];
        pk[1] = gbuf[base + p + 256];
        pk[2] = gbuf[base + p + 512];
        pk[3] = gbuf[base + p + 768];
        float4 r0[4], r1[4], r2[4];
#pragma unroll
        for (int q = 0; q < 4; q++) {
            const float4* xr = (const float4*)(x16 + (size_t)(pk[q] & 131071) * 16);
            r0[q] = xr[0]; r1[q] = xr[1]; r2[q] = xr[2];
        }
#pragma unroll
        for (int q = 0; q < 4; q++) {
            float w = r2[q].w;
            float* u = uloc + (pk[q] >> 17) * 13;
            atomicAdd(&u[0],  w * r0[q].x);
            atomicAdd(&u[1],  w * r0[q].y);
            atomicAdd(&u[2],  w * r0[q].z);
            atomicAdd(&u[3],  w * r0[q].w);
            atomicAdd(&u[4],  w * r1[q].x);
            atomicAdd(&u[5],  w * r1[q].y);
            atomicAdd(&u[6],  w * r1[q].z);
            atomicAdd(&u[7],  w * r1[q].w);
            atomicAdd(&u[8],  w * r2[q].x);
            atomicAdd(&u[9],  w * r2[q].y);
            atomicAdd(&u[10], w * r2[q].z);
        }
    }
    for (; p < hi; p += 256) {
        int pack = gbuf[base + p];
        const float4* xr = (const float4*)(x16 + (size_t)(pack & 131071) * 16);
        float4 a0 = xr[0], a1 = xr[1], a2 = xr[2];
        float w = a2.w;
        float* u = uloc + (pack >> 17) * 13;
        atomicAdd(&u[0],  w * a0.x);
        atomicAdd(&u[1],  w * a0.y);
        atomicAdd(&u[2],  w * a0.z);
        atomicAdd(&u[3],  w * a0.w);
        atomicAdd(&u[4],  w * a1.x);
        atomicAdd(&u[5],  w * a1.y);
        atomicAdd(&u[6],  w * a1.z);
        atomicAdd(&u[7],  w * a1.w);
        atomicAdd(&u[8],  w * a2.x);
        atomicAdd(&u[9],  w * a2.y);
        atomicAdd(&u[10], w * a2.z);
    }
    __syncthreads();
    // flush partial slice (non-atomic; every slot written — ws is poisoned)
    float* dst = upart + ((size_t)s * NPAD_ + (b << 8) + t) * 12;
    float4 v0 = make_float4(uloc[t*13+0], uloc[t*13+1], uloc[t*13+2],  uloc[t*13+3]);
    float4 v1 = make_float4(uloc[t*13+4], uloc[t*13+5], uloc[t*13+6],  uloc[t*13+7]);
    float4 v2 = make_float4(uloc[t*13+8], uloc[t*13+9], uloc[t*13+10], 0.f);
    ((float4*)dst)[0] = v0; ((float4*)dst)[1] = v1; ((float4*)dst)[2] = v2;
}

// ---------------- per-node: sum slices + full transform ---------------------
__global__ __launch_bounds__(256) void k_node(
    const float* __restrict__ upart, const float* __restrict__ x16,
    const float* __restrict__ W1, const float* __restrict__ b1,
    const float* __restrict__ W2,
    float* __restrict__ hd, float* __restrict__ xmean) {
    __shared__ float sW1[D_ * 64];
    __shared__ float sb1[64];
    __shared__ float sW2[75];
    __shared__ float smean[64];
    int t = threadIdx.x;
    for (int k = t; k < D_ * 64; k += 256) sW1[k] = W1[k];
    if (t < 64) { sb1[t] = b1[t]; smean[t] = 0.f; }
    if (t < 75) sW2[t] = W2[t];
    __syncthreads();

    int node = blockIdx.x * 256 + t;
    if (node < N_) {
        float acc[12];
#pragma unroll
        for (int j = 0; j < 12; j++) acc[j] = 0.f;
#pragma unroll
        for (int s = 0; s < S_; s++) {
            const float4* up = (const float4*)(upart + ((size_t)s * NPAD_ + node) * 12);
            float4 u0 = up[0], u1 = up[1], u2 = up[2];
            acc[0] += u0.x; acc[1] += u0.y; acc[2]  += u0.z; acc[3]  += u0.w;
            acc[4] += u1.x; acc[5] += u1.y; acc[6]  += u1.z; acc[7]  += u1.w;
            acc[8] += u2.x; acc[9] += u2.y; acc[10] += u2.z;
        }
        const float4* xs = (const float4*)(x16 + (size_t)node * 16);
        float4 s0 = xs[0], s1 = xs[1], s2 = xs[2];
        float di = s2.w;
        float xr_[D_], g[D_];
        xr_[0]=s0.x; xr_[1]=s0.y; xr_[2]=s0.z; xr_[3]=s0.w;
        xr_[4]=s1.x; xr_[5]=s1.y; xr_[6]=s1.z; xr_[7]=s1.w;
        xr_[8]=s2.x; xr_[9]=s2.y; xr_[10]=s2.z;
#pragma unroll
        for (int j = 0; j < D_; j++) g[j] = di * (acc[j] + di * xr_[j]);

        float h2v = 0.f;
        int f0 = t & 63;  // lane-stagger: no same-address LDS atomic collisions
#pragma unroll 8
        for (int k = 0; k < 64; k++) {
            int f = (f0 + k) & 63;
            float a = sb1[f];
#pragma unroll
            for (int j = 0; j < D_; j++) a = fmaf(g[j], sW1[j * 64 + f], a);
            float hf = fmaxf(a, 0.f);
            atomicAdd(&smean[f], hf);
            h2v = fmaf(hf, sW2[f], h2v);
        }
#pragma unroll
        for (int j = 0; j < D_; j++) h2v = fmaf(xr_[j], sW2[64 + j], h2v);
        hd[node] = di * h2v;  // pre-scaled: conv2 needs dis[d]*h2[d]
    }
    __syncthreads();
    if (t < 64) atomicAdd(&xmean[t], smean[t]);
}

// ---------------- per-bucket-segment conv2: flag-gated accumulate -----------
__global__ __launch_bounds__(256) void k_pr(const int* __restrict__ bcur,
                                            const int* __restrict__ gbuf,
                                            const unsigned char* __restrict__ flag,
                                            const float* __restrict__ hd,
                                            float* __restrict__ pr_raw) {
    __shared__ float prl[256];
    __shared__ unsigned char fl[256];
    int t = threadIdx.x, b = blockIdx.x, s = blockIdx.y;
    prl[t] = 0.f;
    int node = (b << 8) + t;
    fl[t] = (node < N_) ? flag[node] : 0;
    __syncthreads();
    int base = b * CAPB_, cnt = bcur[b] - base;
    int seg = (cnt + S_ - 1) / S_;
    int lo = s * seg, hi = min(lo + seg, cnt);
    for (int p = lo + t; p < hi; p += 256) {
        int pack = gbuf[base + p];
        int sl = pack >> 17;
        if (fl[sl]) atomicAdd(&prl[sl], hd[pack & 131071]);
    }
    __syncthreads();
    if (node < N_ && fl[t] && prl[t] != 0.f) atomicAdd(&pr_raw[node], prl[t]);
}

// ---------------- finalize: logits, prob_nothing, v, softmax ----------------
__global__ __launch_bounds__(1024) void k_final(
    const int* __restrict__ ready, const float* __restrict__ dis,
    const float* __restrict__ hd, const float* __restrict__ pr_raw,
    const float* __restrict__ xmean,
    const float* __restrict__ b2,
    const float* __restrict__ Wd, const float* __restrict__ bd,
    const float* __restrict__ Wv, const float* __restrict__ bv,
    float* __restrict__ out) {
    __shared__ float xm[64];
    __shared__ float red[1024];
    __shared__ float s_max, s_sum, s_pn, s_v;
    int t = threadIdx.x;
    if (t < 64) xm[t] = xmean[t] * (1.0f / N_);
    __syncthreads();
    if (t == 0) {
        float pn = bd[0], vv = bv[0];
        for (int f = 0; f < 64; f++) { pn += xm[f] * Wd[f]; vv += xm[f] * Wv[f]; }
        s_pn = pn; s_v = vv;
    }
    int r = ready[t];
    float dr = dis[r];
    float l = dr * (pr_raw[r] + hd[r]) + b2[0];   // dr*Σhd[d] + dr²h2[r] + b2
    __syncthreads();
    float pn = s_pn;
    red[t] = (t == 0) ? fmaxf(l, pn) : l;
    __syncthreads();
    for (int sft = 512; sft > 0; sft >>= 1) {
        if (t < sft) red[t] = fmaxf(red[t], red[t + sft]);
        __syncthreads();
    }
    if (t == 0) s_max = red[0];
    __syncthreads();
    float m = s_max;
    float el = expf(l - m);
    red[t] = el + ((t == 0) ? expf(pn - m) : 0.f);
    __syncthreads();
    for (int sft = 512; sft > 0; sft >>= 1) {
        if (t < sft) red[t] += red[t + sft];
        __syncthreads();
    }
    if (t == 0) s_sum = red[0];
    __syncthreads();
    float inv = 1.0f / s_sum;
    out[t] = el * inv;
    if (t == 0) {
        out[K_] = expf(pn - m) * inv;   // prob_nothing slot
        out[K_ + 1] = s_v;              // v
    }
}

extern "C" void kernel_launch(void* const* d_in, const int* in_sizes, int n_in,
                              void* d_out, int out_size, void* d_ws, size_t ws_size,
                              hipStream_t stream) {
    const float* x    = (const float*)d_in[0];
    const int*   ei   = (const int*)d_in[1];
    const int*   src  = ei;
    const int*   dst  = ei + E_;
    const int*   ready= (const int*)d_in[2];
    const float* W1   = (const float*)d_in[3];
    const float* b1   = (const float*)d_in[4];
    const float* W2   = (const float*)d_in[5];
    const float* b2   = (const float*)d_in[6];
    const float* Wd   = (const float*)d_in[7];
    const float* bd   = (const float*)d_in[8];
    const float* Wv   = (const float*)d_in[9];
    const float* bv   = (const float*)d_in[10];
    float* out = (float*)d_out;

    char* ws = (char*)d_ws;
    size_t o = 0;
    int*   bcur   = (int*)(ws + o);          o += align512(NBUCK_ * sizeof(int));
    int*   gbuf   = (int*)(ws + o);          o += align512((size_t)NBUCK_ * CAPB_ * sizeof(int));
    float* upart  = (float*)(ws + o);        o += align512((size_t)S_ * NPAD_ * 12 * sizeof(float));
    float* x16    = (float*)(ws + o);        o += align512((size_t)N_ * 16 * sizeof(float));
    int*   deg    = (int*)(ws + o);          o += align512(N_ * sizeof(int));
    float* dis    = (float*)(ws + o);        o += align512(N_ * sizeof(float));
    float* hd     = (float*)(ws + o);        o += align512(N_ * sizeof(float));
    float* pr_raw = (float*)(ws + o);        o += align512(N_ * sizeof(float));
    unsigned char* flag = (unsigned char*)(ws + o); o += align512(N_);
    float* xmean  = (float*)(ws + o);        o += align512(64 * sizeof(float));

    const int B = 256;
    int g_node = (N_ + B - 1) / B;
    int g_pad  = (N_ * 16 + B - 1) / B;
    dim3 gseg(NBUCK_, S_);

    k_init <<<g_node, B, 0, stream>>>(deg, pr_raw, flag, xmean, bcur);
    k_flags<<<(K_ + B - 1) / B, B, 0, stream>>>(ready, flag);
    k_pad  <<<g_pad, B, 0, stream>>>(x, x16);
    k_bin  <<<GB_, B, 0, stream>>>(src, dst, bcur, gbuf);
    k_deg  <<<gseg, B, 0, stream>>>(bcur, gbuf, deg);
    k_dis  <<<g_node, B, 0, stream>>>(deg, dis, x16);
    k_agg  <<<gseg, B, 0, stream>>>(bcur, gbuf, x16, upart);
    k_node <<<g_node, B, 0, stream>>>(upart, x16, W1, b1, W2, hd, xmean);
    k_pr   <<<gseg, B, 0, stream>>>(bcur, gbuf, flag, hd, pr_raw);
    k_final<<<1, 1024, 0, stream>>>(ready, dis, hd, pr_raw, xmean,
                                    b2, Wd, bd, Wv, bv, out);
}